// Round 2
// baseline (828.115 us; speedup 1.0000x reference)
//
#include <hip/hip_runtime.h>

// MoGeSampledLocalLoss: per-patch truncated robust affine depth alignment +
// smooth-L1 loss, global mean over valid patches.
//
// One 64-lane wave per patch (K=256 -> 4 pixels/lane in registers, zero
// memory re-reads). R1 changes:
//  - IEEE divides -> v_rcp_f32 (1 instr vs ~10; threshold 1.5e-2 >> 1e-7 err)
//  - finalize fused via last-block ticket (3 dispatches -> memset + 1 kernel)

#define WPB 4       // waves (patches) per 256-thread block
#define NSLOTS 64   // scatter slots for the global atomic reduction

__device__ __forceinline__ float wred(float v) {
  #pragma unroll
  for (int off = 32; off; off >>= 1) v += __shfl_xor(v, off, 64);
  return v;
}

__device__ __forceinline__ float frcp(float x) {
  return __builtin_amdgcn_rcpf(x);   // ~1 ulp, 1 VALU instr
}

__global__ __launch_bounds__(256) void moge_patch_kernel(
    const float* __restrict__ xg,   // pred_depth (B*N)
    const float* __restrict__ yg,   // gt_depth   (B*N)
    const int*   __restrict__ mg,   // mask       (B*N), 0/1
    const float* __restrict__ gsg,  // global_scale (B)
    const int*   __restrict__ pP,   // num_patches (device scalar)
    const int*   __restrict__ pK,   // patch_pixel_count (device scalar)
    int B,
    float* __restrict__ ws,         // [0..63] loss, [64..127] cnt, [128] ticket
    float* __restrict__ out) {
  const int P = pP[0];
  const int K = pK[0];
  const int lane = threadIdx.x & 63;
  const int wib  = threadIdx.x >> 6;
  const int total_patches = B * P;
  const int wave_stride = gridDim.x * WPB;
  const float invK = 1.0f / (float)K;
  const bool fast = (K == 256);

  for (int patch = blockIdx.x * WPB + wib; patch < total_patches;
       patch += wave_stride) {
    const long base = (long)patch * (long)K;
    const float* xp = xg + base;
    const float* yp = yg + base;
    const int*   mp = mg + base;

    float xr[4], yr[4], mr[4], wr[4];

    // ---- pass 1: WLS sums + mask stats -------------------------------
    float sw = 0.f, swx = 0.f, swy = 0.f, swxx = 0.f, swxy = 0.f;
    float msum = 0.f, symsum = 0.f;
    if (fast) {
      const float4 x4 = *(const float4*)(xp + lane * 4);
      const float4 y4 = *(const float4*)(yp + lane * 4);
      const int4   m4 = *(const int4*)(mp + lane * 4);
      xr[0] = x4.x; xr[1] = x4.y; xr[2] = x4.z; xr[3] = x4.w;
      yr[0] = y4.x; yr[1] = y4.y; yr[2] = y4.z; yr[3] = y4.w;
      mr[0] = m4.x ? 1.f : 0.f; mr[1] = m4.y ? 1.f : 0.f;
      mr[2] = m4.z ? 1.f : 0.f; mr[3] = m4.w ? 1.f : 0.f;
      #pragma unroll
      for (int i = 0; i < 4; ++i) {
        const float m = mr[i], xx = xr[i], yy = yr[i];
        const float w = m * frcp(fmaxf(yy, 1e-5f));
        wr[i] = w;
        const float wx = w * xx;
        sw += w; swx += wx; swy = fmaf(w, yy, swy);
        swxx = fmaf(wx, xx, swxx); swxy = fmaf(wx, yy, swxy);
        msum += m; symsum = fmaf(m, yy, symsum);
      }
    } else {
      for (int j = lane; j < K; j += 64) {
        const float m = mp[j] ? 1.f : 0.f;
        const float xx = xp[j], yy = yp[j];
        const float w = m * frcp(fmaxf(yy, 1e-5f));
        const float wx = w * xx;
        sw += w; swx += wx; swy = fmaf(w, yy, swy);
        swxx = fmaf(wx, xx, swxx); swxy = fmaf(wx, yy, swxy);
        msum += m; symsum = fmaf(m, yy, symsum);
      }
    }
    sw = wred(sw); swx = wred(swx); swy = wred(swy);
    swxx = wred(swxx); swxy = wred(swxy);
    msum = wred(msum); symsum = wred(symsum);

    float det = sw * swxx - swx * swx;
    if (fabsf(det) < 1e-12f) det = 1e-12f;   // jnp.where -> +1e-12 either sign
    float rdet = frcp(det);
    const float s0 = (sw * swxy - swx * swy) * rdet;
    const float t0 = (swxx * swy - swx * swxy) * rdet;

    // ---- pass 2: truncated refit ------------------------------------
    float sw2 = 0.f, swx2 = 0.f, swy2 = 0.f, swxx2 = 0.f, swxy2 = 0.f;
    if (fast) {
      #pragma unroll
      for (int i = 0; i < 4; ++i) {
        const float xx = xr[i], yy = yr[i], w = wr[i];
        const float e = w * fabsf(fmaf(s0, xx, t0) - yy);
        const float w2 = (e < 1.0f) ? w : 0.f;   // TRUNC = 1.0, strict <
        const float w2x = w2 * xx;
        sw2 += w2; swx2 += w2x; swy2 = fmaf(w2, yy, swy2);
        swxx2 = fmaf(w2x, xx, swxx2); swxy2 = fmaf(w2x, yy, swxy2);
      }
    } else {
      for (int j = lane; j < K; j += 64) {
        const float m = mp[j] ? 1.f : 0.f;
        const float xx = xp[j], yy = yp[j];
        const float w = m * frcp(fmaxf(yy, 1e-5f));
        const float e = w * fabsf(fmaf(s0, xx, t0) - yy);
        const float w2 = (e < 1.0f) ? w : 0.f;
        const float w2x = w2 * xx;
        sw2 += w2; swx2 += w2x; swy2 = fmaf(w2, yy, swy2);
        swxx2 = fmaf(w2x, xx, swxx2); swxy2 = fmaf(w2x, yy, swxy2);
      }
    }
    sw2 = wred(sw2); swx2 = wred(swx2); swy2 = wred(swy2);
    swxx2 = wred(swxx2); swxy2 = wred(swxy2);

    if (sw2 > 1e-8f) {  // sum(w2) == sw2; else fall back to pass-1 sums
      sw = sw2; swx = swx2; swy = swy2; swxx = swxx2; swxy = swxy2;
    }
    det = sw * swxx - swx * swx;
    if (fabsf(det) < 1e-12f) det = 1e-12f;
    rdet = frcp(det);
    const float s = (sw * swxy - swx * swy) * rdet;
    const float t = (swxx * swy - swx * swxy) * rdet;

    // ---- pass 3: smooth-L1 patch loss -------------------------------
    const float mean_depth =
        (msum > 0.f) ? (symsum * frcp(fmaxf(msum, 1.f))) : 1.f;
    const float yfloor = 0.1f * mean_depth;

    float lsum = 0.f;
    if (fast) {
      #pragma unroll
      for (int i = 0; i < 4; ++i) {
        const float xx = xr[i], yy = yr[i], m = mr[i];
        const float pw = m * frcp(fmaxf(yy, yfloor));
        const float err = fabsf(fmaf(s, xx, t) - yy) * pw;
        // BETA = 0.1: err<0.1 ? 0.5*err^2/0.1 : err-0.05
        lsum += (err < 0.1f) ? (5.0f * err * err) : (err - 0.05f);
      }
    } else {
      for (int j = lane; j < K; j += 64) {
        const float m = mp[j] ? 1.f : 0.f;
        const float xx = xp[j], yy = yp[j];
        const float pw = m * frcp(fmaxf(yy, yfloor));
        const float err = fabsf(fmaf(s, xx, t) - yy) * pw;
        lsum += (err < 0.1f) ? (5.0f * err * err) : (err - 0.05f);
      }
    }
    lsum = wred(lsum);
    const float patch_loss = lsum * invK;

    // ---- validity + scatter-reduced accumulation --------------------
    const float gs = gsg[patch / P];
    const float ratio = s * frcp(fmaxf(gs, 1e-12f));
    const bool gs_ok = (gs > 0.f) ? (ratio >= 0.1f && ratio <= 10.0f) : true;
    const bool valid = (msum * invK >= 0.3f) && (s > 0.f) && gs_ok;

    if (lane == 0 && valid) {
      const int slot = patch & (NSLOTS - 1);
      atomicAdd(&ws[slot], patch_loss);
      atomicAdd(&ws[NSLOTS + slot], 1.0f);
    }
  }

  // ---- last-block-done finalize (fused) -----------------------------
  __threadfence();      // make this thread's atomics globally visible
  __syncthreads();      // all waves of the block are done
  __shared__ int is_last;
  if (threadIdx.x == 0) {
    unsigned int old = atomicAdd((unsigned int*)(ws + 2 * NSLOTS), 1u);
    is_last = (old == gridDim.x - 1) ? 1 : 0;
  }
  __syncthreads();
  if (is_last && threadIdx.x < 64) {
    __threadfence();    // acquire: see every block's slot atomics
    float l = __hip_atomic_load(&ws[threadIdx.x], __ATOMIC_RELAXED,
                                __HIP_MEMORY_SCOPE_AGENT);
    float c = __hip_atomic_load(&ws[NSLOTS + threadIdx.x], __ATOMIC_RELAXED,
                                __HIP_MEMORY_SCOPE_AGENT);
    l = wred(l);
    c = wred(c);
    if (threadIdx.x == 0) out[0] = (c > 0.f) ? (l / fmaxf(c, 1.f)) : 0.f;
  }
}

extern "C" void kernel_launch(void* const* d_in, const int* in_sizes, int n_in,
                              void* d_out, int out_size, void* d_ws, size_t ws_size,
                              hipStream_t stream) {
  const float* pred = (const float*)d_in[0];
  const float* gt   = (const float*)d_in[1];
  const int*   mask = (const int*)d_in[2];
  const float* gs   = (const float*)d_in[3];
  const int*   pP   = (const int*)d_in[4];
  const int*   pK   = (const int*)d_in[5];
  const int B = in_sizes[3];
  const long total_pixels = (long)in_sizes[0];
  float* ws = (float*)d_ws;

  // slots + ticket counter zeroed by a memset node (cheaper than a kernel)
  hipMemsetAsync(ws, 0, (2 * NSLOTS + 1) * sizeof(float), stream);

  long est_patches = total_pixels / 256;  // grid sized for K=256; grid-stride
  int blocks = (int)((est_patches + WPB - 1) / WPB);
  if (blocks < 1) blocks = 1;
  moge_patch_kernel<<<blocks, 256, 0, stream>>>(pred, gt, mask, gs, pP, pK, B,
                                                ws, (float*)d_out);
}

// Round 3
// 146.429 us; speedup vs baseline: 5.6554x; 5.6554x over previous
//
#include <hip/hip_runtime.h>

// MoGeSampledLocalLoss: per-patch truncated robust affine depth alignment +
// smooth-L1 loss, global mean over valid patches.
//
// One 64-lane wave per patch iteration (K=256 -> 4 pixels/lane in registers,
// zero memory re-reads). R3 changes vs R2:
//  - REMOVED __threadfence() (device acq-rel fence -> buffer_inv sc0 sc1 on
//    gfx950 = per-block L2 invalidate -> thrashed L2 for all running blocks;
//    R2 regressed 43->792 us, VALUBusy 2.9%). __syncthreads() already drains
//    vmcnt, which orders the device-scope slot atomics before the ticket.
//  - single acquire fence only in the LAST block (1 invalidate per kernel).
//  - grid capped at 2048 blocks (8 blocks/CU, 32 waves/CU at VGPR=36);
//    4 patches/wave grid-strided; ticket adds 8192 -> 2048.

#define WPB 4       // waves per 256-thread block
#define NSLOTS 64   // scatter slots for the global atomic reduction
#define MAXBLK 2048

__device__ __forceinline__ float wred(float v) {
  #pragma unroll
  for (int off = 32; off; off >>= 1) v += __shfl_xor(v, off, 64);
  return v;
}

__device__ __forceinline__ float frcp(float x) {
  return __builtin_amdgcn_rcpf(x);   // ~1 ulp, 1 VALU instr
}

__global__ __launch_bounds__(256) void moge_patch_kernel(
    const float* __restrict__ xg,   // pred_depth (B*N)
    const float* __restrict__ yg,   // gt_depth   (B*N)
    const int*   __restrict__ mg,   // mask       (B*N), 0/1
    const float* __restrict__ gsg,  // global_scale (B)
    const int*   __restrict__ pP,   // num_patches (device scalar)
    const int*   __restrict__ pK,   // patch_pixel_count (device scalar)
    int B,
    float* __restrict__ ws,         // [0..63] loss, [64..127] cnt, [128] ticket
    float* __restrict__ out) {
  const int P = pP[0];
  const int K = pK[0];
  const int lane = threadIdx.x & 63;
  const int wib  = threadIdx.x >> 6;
  const int total_patches = B * P;
  const int wave_stride = gridDim.x * WPB;
  const float invK = 1.0f / (float)K;
  const bool fast = (K == 256);

  for (int patch = blockIdx.x * WPB + wib; patch < total_patches;
       patch += wave_stride) {
    const long base = (long)patch * (long)K;
    const float* xp = xg + base;
    const float* yp = yg + base;
    const int*   mp = mg + base;

    float xr[4], yr[4], mr[4], wr[4];

    // ---- pass 1: WLS sums + mask stats -------------------------------
    float sw = 0.f, swx = 0.f, swy = 0.f, swxx = 0.f, swxy = 0.f;
    float msum = 0.f, symsum = 0.f;
    if (fast) {
      const float4 x4 = *(const float4*)(xp + lane * 4);
      const float4 y4 = *(const float4*)(yp + lane * 4);
      const int4   m4 = *(const int4*)(mp + lane * 4);
      xr[0] = x4.x; xr[1] = x4.y; xr[2] = x4.z; xr[3] = x4.w;
      yr[0] = y4.x; yr[1] = y4.y; yr[2] = y4.z; yr[3] = y4.w;
      mr[0] = m4.x ? 1.f : 0.f; mr[1] = m4.y ? 1.f : 0.f;
      mr[2] = m4.z ? 1.f : 0.f; mr[3] = m4.w ? 1.f : 0.f;
      #pragma unroll
      for (int i = 0; i < 4; ++i) {
        const float m = mr[i], xx = xr[i], yy = yr[i];
        const float w = m * frcp(fmaxf(yy, 1e-5f));
        wr[i] = w;
        const float wx = w * xx;
        sw += w; swx += wx; swy = fmaf(w, yy, swy);
        swxx = fmaf(wx, xx, swxx); swxy = fmaf(wx, yy, swxy);
        msum += m; symsum = fmaf(m, yy, symsum);
      }
    } else {
      for (int j = lane; j < K; j += 64) {
        const float m = mp[j] ? 1.f : 0.f;
        const float xx = xp[j], yy = yp[j];
        const float w = m * frcp(fmaxf(yy, 1e-5f));
        const float wx = w * xx;
        sw += w; swx += wx; swy = fmaf(w, yy, swy);
        swxx = fmaf(wx, xx, swxx); swxy = fmaf(wx, yy, swxy);
        msum += m; symsum = fmaf(m, yy, symsum);
      }
    }
    sw = wred(sw); swx = wred(swx); swy = wred(swy);
    swxx = wred(swxx); swxy = wred(swxy);
    msum = wred(msum); symsum = wred(symsum);

    float det = sw * swxx - swx * swx;
    if (fabsf(det) < 1e-12f) det = 1e-12f;   // jnp.where -> +1e-12 either sign
    float rdet = frcp(det);
    const float s0 = (sw * swxy - swx * swy) * rdet;
    const float t0 = (swxx * swy - swx * swxy) * rdet;

    // ---- pass 2: truncated refit ------------------------------------
    float sw2 = 0.f, swx2 = 0.f, swy2 = 0.f, swxx2 = 0.f, swxy2 = 0.f;
    if (fast) {
      #pragma unroll
      for (int i = 0; i < 4; ++i) {
        const float xx = xr[i], yy = yr[i], w = wr[i];
        const float e = w * fabsf(fmaf(s0, xx, t0) - yy);
        const float w2 = (e < 1.0f) ? w : 0.f;   // TRUNC = 1.0, strict <
        const float w2x = w2 * xx;
        sw2 += w2; swx2 += w2x; swy2 = fmaf(w2, yy, swy2);
        swxx2 = fmaf(w2x, xx, swxx2); swxy2 = fmaf(w2x, yy, swxy2);
      }
    } else {
      for (int j = lane; j < K; j += 64) {
        const float m = mp[j] ? 1.f : 0.f;
        const float xx = xp[j], yy = yp[j];
        const float w = m * frcp(fmaxf(yy, 1e-5f));
        const float e = w * fabsf(fmaf(s0, xx, t0) - yy);
        const float w2 = (e < 1.0f) ? w : 0.f;
        const float w2x = w2 * xx;
        sw2 += w2; swx2 += w2x; swy2 = fmaf(w2, yy, swy2);
        swxx2 = fmaf(w2x, xx, swxx2); swxy2 = fmaf(w2x, yy, swxy2);
      }
    }
    sw2 = wred(sw2); swx2 = wred(swx2); swy2 = wred(swy2);
    swxx2 = wred(swxx2); swxy2 = wred(swxy2);

    if (sw2 > 1e-8f) {  // sum(w2) == sw2; else fall back to pass-1 sums
      sw = sw2; swx = swx2; swy = swy2; swxx = swxx2; swxy = swxy2;
    }
    det = sw * swxx - swx * swx;
    if (fabsf(det) < 1e-12f) det = 1e-12f;
    rdet = frcp(det);
    const float s = (sw * swxy - swx * swy) * rdet;
    const float t = (swxx * swy - swx * swxy) * rdet;

    // ---- pass 3: smooth-L1 patch loss -------------------------------
    const float mean_depth =
        (msum > 0.f) ? (symsum * frcp(fmaxf(msum, 1.f))) : 1.f;
    const float yfloor = 0.1f * mean_depth;

    float lsum = 0.f;
    if (fast) {
      #pragma unroll
      for (int i = 0; i < 4; ++i) {
        const float xx = xr[i], yy = yr[i], m = mr[i];
        const float pw = m * frcp(fmaxf(yy, yfloor));
        const float err = fabsf(fmaf(s, xx, t) - yy) * pw;
        // BETA = 0.1: err<0.1 ? 0.5*err^2/0.1 : err-0.05
        lsum += (err < 0.1f) ? (5.0f * err * err) : (err - 0.05f);
      }
    } else {
      for (int j = lane; j < K; j += 64) {
        const float m = mp[j] ? 1.f : 0.f;
        const float xx = xp[j], yy = yp[j];
        const float pw = m * frcp(fmaxf(yy, yfloor));
        const float err = fabsf(fmaf(s, xx, t) - yy) * pw;
        lsum += (err < 0.1f) ? (5.0f * err * err) : (err - 0.05f);
      }
    }
    lsum = wred(lsum);
    const float patch_loss = lsum * invK;

    // ---- validity + scatter-reduced accumulation --------------------
    const float gs = gsg[patch / P];
    const float ratio = s * frcp(fmaxf(gs, 1e-12f));
    const bool gs_ok = (gs > 0.f) ? (ratio >= 0.1f && ratio <= 10.0f) : true;
    const bool valid = (msum * invK >= 0.3f) && (s > 0.f) && gs_ok;

    if (lane == 0 && valid) {
      const int slot = patch & (NSLOTS - 1);
      atomicAdd(&ws[slot], patch_loss);          // device-scope RMW @ coherence pt
      atomicAdd(&ws[NSLOTS + slot], 1.0f);
    }
  }

  // ---- last-block-done finalize (fused, fence-light) ----------------
  // __syncthreads() drains each wave's vmcnt (compiler emits
  // s_waitcnt vmcnt(0) before s_barrier), so all this block's slot RMWs are
  // complete at the coherence point before lane 0's ticket RMW below.
  __syncthreads();
  __shared__ int is_last;
  if (threadIdx.x == 0) {
    unsigned int old = atomicAdd((unsigned int*)(ws + 2 * NSLOTS), 1u);
    is_last = (old == gridDim.x - 1) ? 1 : 0;
  }
  __syncthreads();
  if (is_last && threadIdx.x < 64) {
    // one acquire per kernel (last block only): invalidate possibly-stale
    // cache lines before reading the slots.
    __builtin_amdgcn_fence(__ATOMIC_ACQUIRE, "agent");
    float l = __hip_atomic_load(&ws[threadIdx.x], __ATOMIC_RELAXED,
                                __HIP_MEMORY_SCOPE_AGENT);
    float c = __hip_atomic_load(&ws[NSLOTS + threadIdx.x], __ATOMIC_RELAXED,
                                __HIP_MEMORY_SCOPE_AGENT);
    l = wred(l);
    c = wred(c);
    if (threadIdx.x == 0) out[0] = (c > 0.f) ? (l / fmaxf(c, 1.f)) : 0.f;
  }
}

extern "C" void kernel_launch(void* const* d_in, const int* in_sizes, int n_in,
                              void* d_out, int out_size, void* d_ws, size_t ws_size,
                              hipStream_t stream) {
  const float* pred = (const float*)d_in[0];
  const float* gt   = (const float*)d_in[1];
  const int*   mask = (const int*)d_in[2];
  const float* gs   = (const float*)d_in[3];
  const int*   pP   = (const int*)d_in[4];
  const int*   pK   = (const int*)d_in[5];
  const int B = in_sizes[3];
  const long total_pixels = (long)in_sizes[0];
  float* ws = (float*)d_ws;

  // slots + ticket counter zeroed by a memset node
  hipMemsetAsync(ws, 0, (2 * NSLOTS + 1) * sizeof(float), stream);

  long est_patches = total_pixels / 256;  // grid sized for K=256; grid-stride
  long blocks = (est_patches + WPB - 1) / WPB;
  if (blocks < 1) blocks = 1;
  if (blocks > MAXBLK) blocks = MAXBLK;   // 8 blocks/CU, 4 patches/wave
  moge_patch_kernel<<<(int)blocks, 256, 0, stream>>>(pred, gt, mask, gs, pP,
                                                     pK, B, ws, (float*)d_out);
}

// Round 4
// 144.083 us; speedup vs baseline: 5.7475x; 1.0163x over previous
//
#include <hip/hip_runtime.h>

// MoGeSampledLocalLoss: per-patch truncated robust affine depth alignment +
// smooth-L1 loss, global mean over valid patches.
//
// One 64-lane wave per patch (K=256 -> 4 pixels/lane in registers).
// R4 changes vs R3 (47 us, latency-bound: VALU 35%, HBM 13%):
//  - wave reductions: ds_bpermute butterflies -> DPP row_shr/row_bcast chain
//    (full-rate VALU, ~4cyc dep latency vs ~30cyc LDS round-trip; result
//    lands in SGPR via readlane 63 = free broadcast).
//  - msum/symsum reductions deferred into the pass-2 batch (shorter
//    load->s0 critical path; batches of 5/7/1 chains for ILP).
//  - software prefetch of next patch's x4/y4/m4 before current compute
//    (hides global-load latency for 3 of 4 patches per wave).
//  - finalize stays fused, fence-light (R3 pattern: no per-block
//    __threadfence, single agent-acquire in the last block only).

#define WPB 4       // waves per 256-thread block
#define NSLOTS 64   // scatter slots for the global atomic reduction
#define MAXBLK 2048

// Full-wave sum -> wave-uniform scalar (classic GCN DPP reduction).
// row_shr:1/2/4/8 reduce each row of 16; row_bcast:15/31 merge rows;
// lane 63 holds the total; readlane broadcasts it as an SGPR.
__device__ __forceinline__ float wredu(float v) {
#define DPP_ADD(ctrl)                                                        \
  v += __int_as_float(__builtin_amdgcn_update_dpp(                           \
      0, __float_as_int(v), (ctrl), 0xf, 0xf, true))
  DPP_ADD(0x111);  // row_shr:1
  DPP_ADD(0x112);  // row_shr:2
  DPP_ADD(0x114);  // row_shr:4
  DPP_ADD(0x118);  // row_shr:8
  DPP_ADD(0x142);  // row_bcast:15
  DPP_ADD(0x143);  // row_bcast:31
#undef DPP_ADD
  return __int_as_float(__builtin_amdgcn_readlane(__float_as_int(v), 63));
}

__device__ __forceinline__ float frcp(float x) {
  return __builtin_amdgcn_rcpf(x);   // ~1 ulp, 1 VALU instr
}

__global__ __launch_bounds__(256) void moge_patch_kernel(
    const float* __restrict__ xg,   // pred_depth (B*N)
    const float* __restrict__ yg,   // gt_depth   (B*N)
    const int*   __restrict__ mg,   // mask       (B*N), 0/1
    const float* __restrict__ gsg,  // global_scale (B)
    const int*   __restrict__ pP,   // num_patches (device scalar)
    const int*   __restrict__ pK,   // patch_pixel_count (device scalar)
    int B,
    float* __restrict__ ws,         // [0..63] loss, [64..127] cnt, [128] ticket
    float* __restrict__ out) {
  const int P = pP[0];
  const int K = pK[0];
  const int lane = threadIdx.x & 63;
  const int wib  = threadIdx.x >> 6;
  const int total_patches = B * P;
  const int wave_stride = gridDim.x * WPB;
  const float invK = 1.0f / (float)K;

  if (K == 256) {
    // ---------------- fast path: 4 pixels/lane, prefetched ------------
    int patch = blockIdx.x * WPB + wib;
    if (patch < total_patches) {
      const int loff = lane * 4;
      long base = (long)patch * 256 + loff;
      float4 x4 = *(const float4*)(xg + base);
      float4 y4 = *(const float4*)(yg + base);
      int4   m4 = *(const int4*)(mg + base);

      for (;;) {
        // -- prefetch next patch (clamped addr keeps it branch-free) ---
        const int next = patch + wave_stride;
        const bool has_next = next < total_patches;
        const long nbase = (has_next ? (long)next * 256 : 0) + loff;
        const float4 nx4 = *(const float4*)(xg + nbase);
        const float4 ny4 = *(const float4*)(yg + nbase);
        const int4   nm4 = *(const int4*)(mg + nbase);

        float xr[4] = {x4.x, x4.y, x4.z, x4.w};
        float yr[4] = {y4.x, y4.y, y4.z, y4.w};
        float mr[4] = {m4.x ? 1.f : 0.f, m4.y ? 1.f : 0.f,
                       m4.z ? 1.f : 0.f, m4.w ? 1.f : 0.f};
        float wr[4];

        // -- pass 1: WLS sums (msum/symsum reduced later) --------------
        float sw = 0.f, swx = 0.f, swy = 0.f, swxx = 0.f, swxy = 0.f;
        float msum = 0.f, symsum = 0.f;
        #pragma unroll
        for (int i = 0; i < 4; ++i) {
          const float m = mr[i], xx = xr[i], yy = yr[i];
          const float w = m * frcp(fmaxf(yy, 1e-5f));
          wr[i] = w;
          const float wx = w * xx;
          sw += w; swx += wx; swy = fmaf(w, yy, swy);
          swxx = fmaf(wx, xx, swxx); swxy = fmaf(wx, yy, swxy);
          msum += m; symsum = fmaf(m, yy, symsum);
        }
        sw = wredu(sw); swx = wredu(swx); swy = wredu(swy);
        swxx = wredu(swxx); swxy = wredu(swxy);

        float det = sw * swxx - swx * swx;
        if (fabsf(det) < 1e-12f) det = 1e-12f;  // jnp.where -> +1e-12 any sign
        float rdet = frcp(det);
        const float s0 = (sw * swxy - swx * swy) * rdet;
        const float t0 = (swxx * swy - swx * swxy) * rdet;

        // -- pass 2: truncated refit (+ deferred mask stats) -----------
        float sw2 = 0.f, swx2 = 0.f, swy2 = 0.f, swxx2 = 0.f, swxy2 = 0.f;
        #pragma unroll
        for (int i = 0; i < 4; ++i) {
          const float xx = xr[i], yy = yr[i], w = wr[i];
          const float e = w * fabsf(fmaf(s0, xx, t0) - yy);
          const float w2 = (e < 1.0f) ? w : 0.f;  // TRUNC = 1.0, strict <
          const float w2x = w2 * xx;
          sw2 += w2; swx2 += w2x; swy2 = fmaf(w2, yy, swy2);
          swxx2 = fmaf(w2x, xx, swxx2); swxy2 = fmaf(w2x, yy, swxy2);
        }
        sw2 = wredu(sw2); swx2 = wredu(swx2); swy2 = wredu(swy2);
        swxx2 = wredu(swxx2); swxy2 = wredu(swxy2);
        msum = wredu(msum); symsum = wredu(symsum);

        if (sw2 > 1e-8f) {  // sum(w2)==sw2; else fall back to pass-1 sums
          sw = sw2; swx = swx2; swy = swy2; swxx = swxx2; swxy = swxy2;
        }
        det = sw * swxx - swx * swx;
        if (fabsf(det) < 1e-12f) det = 1e-12f;
        rdet = frcp(det);
        const float s = (sw * swxy - swx * swy) * rdet;
        const float t = (swxx * swy - swx * swxy) * rdet;

        // -- pass 3: smooth-L1 patch loss ------------------------------
        const float mean_depth =
            (msum > 0.f) ? (symsum * frcp(fmaxf(msum, 1.f))) : 1.f;
        const float yfloor = 0.1f * mean_depth;

        float lsum = 0.f;
        #pragma unroll
        for (int i = 0; i < 4; ++i) {
          const float pw = mr[i] * frcp(fmaxf(yr[i], yfloor));
          const float err = fabsf(fmaf(s, xr[i], t) - yr[i]) * pw;
          // BETA = 0.1: err<0.1 ? 0.5*err^2/0.1 : err-0.05
          lsum += (err < 0.1f) ? (5.0f * err * err) : (err - 0.05f);
        }
        const float patch_loss = wredu(lsum) * invK;

        // -- validity + scatter-reduced accumulation -------------------
        const float gs = gsg[patch / P];
        const float ratio = s * frcp(fmaxf(gs, 1e-12f));
        const bool gs_ok = (gs > 0.f) ? (ratio >= 0.1f && ratio <= 10.0f) : true;
        const bool valid = (msum * invK >= 0.3f) && (s > 0.f) && gs_ok;

        if (lane == 0 && valid) {
          const int slot = patch & (NSLOTS - 1);
          atomicAdd(&ws[slot], patch_loss);
          atomicAdd(&ws[NSLOTS + slot], 1.0f);
        }

        if (!has_next) break;
        patch = next; x4 = nx4; y4 = ny4; m4 = nm4;
      }
    }
  } else {
    // ---------------- generic path (any K) ----------------------------
    for (int patch = blockIdx.x * WPB + wib; patch < total_patches;
         patch += wave_stride) {
      const long base = (long)patch * (long)K;
      const float* xp = xg + base;
      const float* yp = yg + base;
      const int*   mp = mg + base;

      float sw = 0.f, swx = 0.f, swy = 0.f, swxx = 0.f, swxy = 0.f;
      float msum = 0.f, symsum = 0.f;
      for (int j = lane; j < K; j += 64) {
        const float m = mp[j] ? 1.f : 0.f;
        const float xx = xp[j], yy = yp[j];
        const float w = m * frcp(fmaxf(yy, 1e-5f));
        const float wx = w * xx;
        sw += w; swx += wx; swy = fmaf(w, yy, swy);
        swxx = fmaf(wx, xx, swxx); swxy = fmaf(wx, yy, swxy);
        msum += m; symsum = fmaf(m, yy, symsum);
      }
      sw = wredu(sw); swx = wredu(swx); swy = wredu(swy);
      swxx = wredu(swxx); swxy = wredu(swxy);
      msum = wredu(msum); symsum = wredu(symsum);

      float det = sw * swxx - swx * swx;
      if (fabsf(det) < 1e-12f) det = 1e-12f;
      float rdet = frcp(det);
      const float s0 = (sw * swxy - swx * swy) * rdet;
      const float t0 = (swxx * swy - swx * swxy) * rdet;

      float sw2 = 0.f, swx2 = 0.f, swy2 = 0.f, swxx2 = 0.f, swxy2 = 0.f;
      for (int j = lane; j < K; j += 64) {
        const float m = mp[j] ? 1.f : 0.f;
        const float xx = xp[j], yy = yp[j];
        const float w = m * frcp(fmaxf(yy, 1e-5f));
        const float e = w * fabsf(fmaf(s0, xx, t0) - yy);
        const float w2 = (e < 1.0f) ? w : 0.f;
        const float w2x = w2 * xx;
        sw2 += w2; swx2 += w2x; swy2 = fmaf(w2, yy, swy2);
        swxx2 = fmaf(w2x, xx, swxx2); swxy2 = fmaf(w2x, yy, swxy2);
      }
      sw2 = wredu(sw2); swx2 = wredu(swx2); swy2 = wredu(swy2);
      swxx2 = wredu(swxx2); swxy2 = wredu(swxy2);

      if (sw2 > 1e-8f) {
        sw = sw2; swx = swx2; swy = swy2; swxx = swxx2; swxy = swxy2;
      }
      det = sw * swxx - swx * swx;
      if (fabsf(det) < 1e-12f) det = 1e-12f;
      rdet = frcp(det);
      const float s = (sw * swxy - swx * swy) * rdet;
      const float t = (swxx * swy - swx * swxy) * rdet;

      const float mean_depth =
          (msum > 0.f) ? (symsum * frcp(fmaxf(msum, 1.f))) : 1.f;
      const float yfloor = 0.1f * mean_depth;

      float lsum = 0.f;
      for (int j = lane; j < K; j += 64) {
        const float m = mp[j] ? 1.f : 0.f;
        const float xx = xp[j], yy = yp[j];
        const float pw = m * frcp(fmaxf(yy, yfloor));
        const float err = fabsf(fmaf(s, xx, t) - yy) * pw;
        lsum += (err < 0.1f) ? (5.0f * err * err) : (err - 0.05f);
      }
      const float patch_loss = wredu(lsum) * invK;

      const float gs = gsg[patch / P];
      const float ratio = s * frcp(fmaxf(gs, 1e-12f));
      const bool gs_ok = (gs > 0.f) ? (ratio >= 0.1f && ratio <= 10.0f) : true;
      const bool valid = (msum * invK >= 0.3f) && (s > 0.f) && gs_ok;

      if (lane == 0 && valid) {
        const int slot = patch & (NSLOTS - 1);
        atomicAdd(&ws[slot], patch_loss);
        atomicAdd(&ws[NSLOTS + slot], 1.0f);
      }
    }
  }

  // ---- last-block-done finalize (fused, fence-light) ----------------
  // __syncthreads() drains each wave's vmcnt, so this block's device-scope
  // slot RMWs are complete at the coherence point before the ticket RMW.
  __syncthreads();
  __shared__ int is_last;
  if (threadIdx.x == 0) {
    unsigned int old = atomicAdd((unsigned int*)(ws + 2 * NSLOTS), 1u);
    is_last = (old == gridDim.x - 1) ? 1 : 0;
  }
  __syncthreads();
  if (is_last && threadIdx.x < 64) {
    // single acquire per kernel (last block only)
    __builtin_amdgcn_fence(__ATOMIC_ACQUIRE, "agent");
    float l = __hip_atomic_load(&ws[threadIdx.x], __ATOMIC_RELAXED,
                                __HIP_MEMORY_SCOPE_AGENT);
    float c = __hip_atomic_load(&ws[NSLOTS + threadIdx.x], __ATOMIC_RELAXED,
                                __HIP_MEMORY_SCOPE_AGENT);
    l = wredu(l);
    c = wredu(c);
    if (threadIdx.x == 0) out[0] = (c > 0.f) ? (l / fmaxf(c, 1.f)) : 0.f;
  }
}

extern "C" void kernel_launch(void* const* d_in, const int* in_sizes, int n_in,
                              void* d_out, int out_size, void* d_ws, size_t ws_size,
                              hipStream_t stream) {
  const float* pred = (const float*)d_in[0];
  const float* gt   = (const float*)d_in[1];
  const int*   mask = (const int*)d_in[2];
  const float* gs   = (const float*)d_in[3];
  const int*   pP   = (const int*)d_in[4];
  const int*   pK   = (const int*)d_in[5];
  const int B = in_sizes[3];
  const long total_pixels = (long)in_sizes[0];
  float* ws = (float*)d_ws;

  // slots + ticket counter zeroed by a memset node
  hipMemsetAsync(ws, 0, (2 * NSLOTS + 1) * sizeof(float), stream);

  long est_patches = total_pixels / 256;  // grid sized for K=256; grid-stride
  long blocks = (est_patches + WPB - 1) / WPB;
  if (blocks < 1) blocks = 1;
  if (blocks > MAXBLK) blocks = MAXBLK;   // 8 blocks/CU, 4 patches/wave
  moge_patch_kernel<<<(int)blocks, 256, 0, stream>>>(pred, gt, mask, gs, pP,
                                                     pK, B, ws, (float*)d_out);
}

// Round 5
// 128.904 us; speedup vs baseline: 6.4243x; 1.1178x over previous
//
#include <hip/hip_runtime.h>

// MoGeSampledLocalLoss: per-patch truncated robust affine depth alignment +
// smooth-L1 loss, global mean over valid patches.
//
// One 64-lane wave per patch (K=256 -> 4 pixels/lane in registers).
// R5 theory: R1-R4 all pinned at 43-47us regardless of VALU cost -> fixed
// external serializer = 65536 device atomics onto 4 cache lines (slot
// arrays), ~16k same-line RMWs @ ~4-8cyc = the whole kernel time; every
// wave's final s_waitcnt vmcnt(0) blocks on the drain.
// R5 changes:
//  - per-wave (loss,cnt) accumulation in registers -> per-block LDS reduce
//    -> 2 atomics per BLOCK (4096 total) spread over 64 distinct cache
//    lines (slot=blockIdx&63; loss+cnt adjacent in one 128B line).
//  - ticket + fused finalize dropped (dispatch count is free per R1 vs
//    R3/R4 totals; ticket was 2048 same-address RMWs). Tiny finalize kernel.

#define WPB 4        // waves per 256-thread block
#define NSLOTS 64    // slots, each on its own 128-B cache line (32 floats)
#define MAXBLK 2048

// Full-wave sum -> wave-uniform scalar (DPP row_shr + row_bcast chain).
__device__ __forceinline__ float wredu(float v) {
#define DPP_ADD(ctrl)                                                        \
  v += __int_as_float(__builtin_amdgcn_update_dpp(                           \
      0, __float_as_int(v), (ctrl), 0xf, 0xf, true))
  DPP_ADD(0x111);  // row_shr:1
  DPP_ADD(0x112);  // row_shr:2
  DPP_ADD(0x114);  // row_shr:4
  DPP_ADD(0x118);  // row_shr:8
  DPP_ADD(0x142);  // row_bcast:15
  DPP_ADD(0x143);  // row_bcast:31
#undef DPP_ADD
  return __int_as_float(__builtin_amdgcn_readlane(__float_as_int(v), 63));
}

__device__ __forceinline__ float frcp(float x) {
  return __builtin_amdgcn_rcpf(x);   // ~1 ulp, 1 VALU instr
}

__global__ __launch_bounds__(256) void moge_patch_kernel(
    const float* __restrict__ xg,   // pred_depth (B*N)
    const float* __restrict__ yg,   // gt_depth   (B*N)
    const int*   __restrict__ mg,   // mask       (B*N), 0/1
    const float* __restrict__ gsg,  // global_scale (B)
    const int*   __restrict__ pP,   // num_patches (device scalar)
    const int*   __restrict__ pK,   // patch_pixel_count (device scalar)
    int B,
    float* __restrict__ ws) {       // NSLOTS lines: [slot*32]=loss,[+1]=cnt
  const int P = pP[0];
  const int K = pK[0];
  const int lane = threadIdx.x & 63;
  const int wib  = threadIdx.x >> 6;
  const int total_patches = B * P;
  const int wave_stride = gridDim.x * WPB;
  const float invK = 1.0f / (float)K;

  float wloss = 0.f, wcnt = 0.f;    // per-wave accumulators (wave-uniform)

  if (K == 256) {
    // ---------------- fast path: 4 pixels/lane, prefetched ------------
    int patch = blockIdx.x * WPB + wib;
    if (patch < total_patches) {
      const int loff = lane * 4;
      long base = (long)patch * 256 + loff;
      float4 x4 = *(const float4*)(xg + base);
      float4 y4 = *(const float4*)(yg + base);
      int4   m4 = *(const int4*)(mg + base);

      for (;;) {
        // -- prefetch next patch (clamped addr keeps it branch-free) ---
        const int next = patch + wave_stride;
        const bool has_next = next < total_patches;
        const long nbase = (has_next ? (long)next * 256 : 0) + loff;
        const float4 nx4 = *(const float4*)(xg + nbase);
        const float4 ny4 = *(const float4*)(yg + nbase);
        const int4   nm4 = *(const int4*)(mg + nbase);

        float xr[4] = {x4.x, x4.y, x4.z, x4.w};
        float yr[4] = {y4.x, y4.y, y4.z, y4.w};
        float mr[4] = {m4.x ? 1.f : 0.f, m4.y ? 1.f : 0.f,
                       m4.z ? 1.f : 0.f, m4.w ? 1.f : 0.f};
        float wr[4];

        // -- pass 1: WLS sums (msum/symsum reduced later) --------------
        float sw = 0.f, swx = 0.f, swy = 0.f, swxx = 0.f, swxy = 0.f;
        float msum = 0.f, symsum = 0.f;
        #pragma unroll
        for (int i = 0; i < 4; ++i) {
          const float m = mr[i], xx = xr[i], yy = yr[i];
          const float w = m * frcp(fmaxf(yy, 1e-5f));
          wr[i] = w;
          const float wx = w * xx;
          sw += w; swx += wx; swy = fmaf(w, yy, swy);
          swxx = fmaf(wx, xx, swxx); swxy = fmaf(wx, yy, swxy);
          msum += m; symsum = fmaf(m, yy, symsum);
        }
        sw = wredu(sw); swx = wredu(swx); swy = wredu(swy);
        swxx = wredu(swxx); swxy = wredu(swxy);

        float det = sw * swxx - swx * swx;
        if (fabsf(det) < 1e-12f) det = 1e-12f;  // jnp.where -> +1e-12 any sign
        float rdet = frcp(det);
        const float s0 = (sw * swxy - swx * swy) * rdet;
        const float t0 = (swxx * swy - swx * swxy) * rdet;

        // -- pass 2: truncated refit (+ deferred mask stats) -----------
        float sw2 = 0.f, swx2 = 0.f, swy2 = 0.f, swxx2 = 0.f, swxy2 = 0.f;
        #pragma unroll
        for (int i = 0; i < 4; ++i) {
          const float xx = xr[i], yy = yr[i], w = wr[i];
          const float e = w * fabsf(fmaf(s0, xx, t0) - yy);
          const float w2 = (e < 1.0f) ? w : 0.f;  // TRUNC = 1.0, strict <
          const float w2x = w2 * xx;
          sw2 += w2; swx2 += w2x; swy2 = fmaf(w2, yy, swy2);
          swxx2 = fmaf(w2x, xx, swxx2); swxy2 = fmaf(w2x, yy, swxy2);
        }
        sw2 = wredu(sw2); swx2 = wredu(swx2); swy2 = wredu(swy2);
        swxx2 = wredu(swxx2); swxy2 = wredu(swxy2);
        msum = wredu(msum); symsum = wredu(symsum);

        if (sw2 > 1e-8f) {  // sum(w2)==sw2; else fall back to pass-1 sums
          sw = sw2; swx = swx2; swy = swy2; swxx = swxx2; swxy = swxy2;
        }
        det = sw * swxx - swx * swx;
        if (fabsf(det) < 1e-12f) det = 1e-12f;
        rdet = frcp(det);
        const float s = (sw * swxy - swx * swy) * rdet;
        const float t = (swxx * swy - swx * swxy) * rdet;

        // -- pass 3: smooth-L1 patch loss ------------------------------
        const float mean_depth =
            (msum > 0.f) ? (symsum * frcp(fmaxf(msum, 1.f))) : 1.f;
        const float yfloor = 0.1f * mean_depth;

        float lsum = 0.f;
        #pragma unroll
        for (int i = 0; i < 4; ++i) {
          const float pw = mr[i] * frcp(fmaxf(yr[i], yfloor));
          const float err = fabsf(fmaf(s, xr[i], t) - yr[i]) * pw;
          // BETA = 0.1: err<0.1 ? 0.5*err^2/0.1 : err-0.05
          lsum += (err < 0.1f) ? (5.0f * err * err) : (err - 0.05f);
        }
        const float patch_loss = wredu(lsum) * invK;

        // -- validity, accumulate in registers (no atomics here) -------
        const float gs = gsg[patch / P];
        const float ratio = s * frcp(fmaxf(gs, 1e-12f));
        const bool gs_ok = (gs > 0.f) ? (ratio >= 0.1f && ratio <= 10.0f) : true;
        const bool valid = (msum * invK >= 0.3f) && (s > 0.f) && gs_ok;

        if (valid) { wloss += patch_loss; wcnt += 1.f; }

        if (!has_next) break;
        patch = next; x4 = nx4; y4 = ny4; m4 = nm4;
      }
    }
  } else {
    // ---------------- generic path (any K) ----------------------------
    for (int patch = blockIdx.x * WPB + wib; patch < total_patches;
         patch += wave_stride) {
      const long base = (long)patch * (long)K;
      const float* xp = xg + base;
      const float* yp = yg + base;
      const int*   mp = mg + base;

      float sw = 0.f, swx = 0.f, swy = 0.f, swxx = 0.f, swxy = 0.f;
      float msum = 0.f, symsum = 0.f;
      for (int j = lane; j < K; j += 64) {
        const float m = mp[j] ? 1.f : 0.f;
        const float xx = xp[j], yy = yp[j];
        const float w = m * frcp(fmaxf(yy, 1e-5f));
        const float wx = w * xx;
        sw += w; swx += wx; swy = fmaf(w, yy, swy);
        swxx = fmaf(wx, xx, swxx); swxy = fmaf(wx, yy, swxy);
        msum += m; symsum = fmaf(m, yy, symsum);
      }
      sw = wredu(sw); swx = wredu(swx); swy = wredu(swy);
      swxx = wredu(swxx); swxy = wredu(swxy);
      msum = wredu(msum); symsum = wredu(symsum);

      float det = sw * swxx - swx * swx;
      if (fabsf(det) < 1e-12f) det = 1e-12f;
      float rdet = frcp(det);
      const float s0 = (sw * swxy - swx * swy) * rdet;
      const float t0 = (swxx * swy - swx * swxy) * rdet;

      float sw2 = 0.f, swx2 = 0.f, swy2 = 0.f, swxx2 = 0.f, swxy2 = 0.f;
      for (int j = lane; j < K; j += 64) {
        const float m = mp[j] ? 1.f : 0.f;
        const float xx = xp[j], yy = yp[j];
        const float w = m * frcp(fmaxf(yy, 1e-5f));
        const float e = w * fabsf(fmaf(s0, xx, t0) - yy);
        const float w2 = (e < 1.0f) ? w : 0.f;
        const float w2x = w2 * xx;
        sw2 += w2; swx2 += w2x; swy2 = fmaf(w2, yy, swy2);
        swxx2 = fmaf(w2x, xx, swxx2); swxy2 = fmaf(w2x, yy, swxy2);
      }
      sw2 = wredu(sw2); swx2 = wredu(swx2); swy2 = wredu(swy2);
      swxx2 = wredu(swxx2); swxy2 = wredu(swxy2);

      if (sw2 > 1e-8f) {
        sw = sw2; swx = swx2; swy = swy2; swxx = swxx2; swxy = swxy2;
      }
      det = sw * swxx - swx * swx;
      if (fabsf(det) < 1e-12f) det = 1e-12f;
      rdet = frcp(det);
      const float s = (sw * swxy - swx * swy) * rdet;
      const float t = (swxx * swy - swx * swxy) * rdet;

      const float mean_depth =
          (msum > 0.f) ? (symsum * frcp(fmaxf(msum, 1.f))) : 1.f;
      const float yfloor = 0.1f * mean_depth;

      float lsum = 0.f;
      for (int j = lane; j < K; j += 64) {
        const float m = mp[j] ? 1.f : 0.f;
        const float xx = xp[j], yy = yp[j];
        const float pw = m * frcp(fmaxf(yy, yfloor));
        const float err = fabsf(fmaf(s, xx, t) - yy) * pw;
        lsum += (err < 0.1f) ? (5.0f * err * err) : (err - 0.05f);
      }
      const float patch_loss = wredu(lsum) * invK;

      const float gs = gsg[patch / P];
      const float ratio = s * frcp(fmaxf(gs, 1e-12f));
      const bool gs_ok = (gs > 0.f) ? (ratio >= 0.1f && ratio <= 10.0f) : true;
      const bool valid = (msum * invK >= 0.3f) && (s > 0.f) && gs_ok;

      if (valid) { wloss += patch_loss; wcnt += 1.f; }
    }
  }

  // ---- block reduce (LDS) -> 2 atomics per block --------------------
  __shared__ float sl[WPB], sc[WPB];
  if (lane == 0) { sl[wib] = wloss; sc[wib] = wcnt; }
  __syncthreads();
  if (threadIdx.x == 0) {
    float bl = 0.f, bc = 0.f;
    #pragma unroll
    for (int i = 0; i < WPB; ++i) { bl += sl[i]; bc += sc[i]; }
    const int slot = (blockIdx.x & (NSLOTS - 1)) * 32;  // own 128-B line
    atomicAdd(&ws[slot], bl);
    atomicAdd(&ws[slot + 1], bc);
  }
}

__global__ void finalize_kernel(const float* __restrict__ ws,
                                float* __restrict__ out) {
  const int t = threadIdx.x;  // 64 threads
  float l = wredu(ws[t * 32]);
  float c = wredu(ws[t * 32 + 1]);
  if (t == 0) out[0] = (c > 0.f) ? (l / fmaxf(c, 1.f)) : 0.f;
}

extern "C" void kernel_launch(void* const* d_in, const int* in_sizes, int n_in,
                              void* d_out, int out_size, void* d_ws, size_t ws_size,
                              hipStream_t stream) {
  const float* pred = (const float*)d_in[0];
  const float* gt   = (const float*)d_in[1];
  const int*   mask = (const int*)d_in[2];
  const float* gs   = (const float*)d_in[3];
  const int*   pP   = (const int*)d_in[4];
  const int*   pK   = (const int*)d_in[5];
  const int B = in_sizes[3];
  const long total_pixels = (long)in_sizes[0];
  float* ws = (float*)d_ws;

  // 64 slot-lines zeroed by a memset node (8 KB)
  hipMemsetAsync(ws, 0, NSLOTS * 32 * sizeof(float), stream);

  long est_patches = total_pixels / 256;  // grid sized for K=256; grid-stride
  long blocks = (est_patches + WPB - 1) / WPB;
  if (blocks < 1) blocks = 1;
  if (blocks > MAXBLK) blocks = MAXBLK;   // 8 blocks/CU, 4 patches/wave
  moge_patch_kernel<<<(int)blocks, 256, 0, stream>>>(pred, gt, mask, gs, pP,
                                                     pK, B, ws);
  finalize_kernel<<<1, 64, 0, stream>>>(ws, (float*)d_out);
}

// Round 6
// 127.938 us; speedup vs baseline: 6.4728x; 1.0076x over previous
//
#include <hip/hip_runtime.h>

// MoGeSampledLocalLoss: per-patch truncated robust affine depth alignment +
// smooth-L1 loss, global mean over valid patches.
//
// R6 structure: one patch per DPP ROW (16 lanes), 16 pixels/lane, so each
// wave processes 4 patches SIMULTANEOUSLY. Row reduction = 4 fused DPP
// row_ror adds (result lands in ALL 16 lanes -> no readlane, no broadcast).
// Per 4 patches: 52 reduction instrs (was 312 DPP + 52 readlane) and the
// patch solve math is computed once vector-wide for 4 patches (was 4x).
// History: R1-R4 pinned at 43-47us by 65k same-line device atomics (fixed in
// R5 via per-block scatter slots, ->~29us, VALU-issue-bound); R6 attacks the
// instruction count. Harness overhead (256MB d_ws repoison ~40us + input
// restores) is fixed at ~100us and not addressable from the kernel.

#define WPB 4        // waves per 256-thread block
#define PPW 4        // patches per wave (one per DPP row)
#define NSLOTS 64    // scatter slots, each on its own 128-B cache line
#define MAXBLK 2048

// Full-wave sum -> wave-uniform scalar (DPP row_shr + row_bcast + readlane).
__device__ __forceinline__ float wredu(float v) {
#define DPP_ADD(ctrl)                                                        \
  v += __int_as_float(__builtin_amdgcn_update_dpp(                           \
      0, __float_as_int(v), (ctrl), 0xf, 0xf, true))
  DPP_ADD(0x111);  // row_shr:1
  DPP_ADD(0x112);  // row_shr:2
  DPP_ADD(0x114);  // row_shr:4
  DPP_ADD(0x118);  // row_shr:8
  DPP_ADD(0x142);  // row_bcast:15
  DPP_ADD(0x143);  // row_bcast:31
#undef DPP_ADD
  return __int_as_float(__builtin_amdgcn_readlane(__float_as_int(v), 63));
}

// Sum across the 16 lanes of each DPP row; EVERY lane of the row ends with
// the row total (rotation-add is a circulant reduction: spans 2,4,8,16).
__device__ __forceinline__ float rowredu(float v) {
#define DPP_ADD(ctrl)                                                        \
  v += __int_as_float(__builtin_amdgcn_update_dpp(                           \
      0, __float_as_int(v), (ctrl), 0xf, 0xf, true))
  DPP_ADD(0x121);  // row_ror:1
  DPP_ADD(0x122);  // row_ror:2
  DPP_ADD(0x124);  // row_ror:4
  DPP_ADD(0x128);  // row_ror:8
#undef DPP_ADD
  return v;
}

__device__ __forceinline__ float frcp(float x) {
  return __builtin_amdgcn_rcpf(x);   // ~1 ulp, 1 VALU instr
}

__global__ __launch_bounds__(256) void moge_patch_kernel(
    const float* __restrict__ xg,   // pred_depth (B*N)
    const float* __restrict__ yg,   // gt_depth   (B*N)
    const int*   __restrict__ mg,   // mask       (B*N), 0/1
    const float* __restrict__ gsg,  // global_scale (B)
    const int*   __restrict__ pP,   // num_patches (device scalar)
    const int*   __restrict__ pK,   // patch_pixel_count (device scalar)
    int B,
    float* __restrict__ ws) {       // NSLOTS lines: [slot*32]=loss,[+1]=cnt
  const int P = pP[0];
  const int K = pK[0];
  const int lane = threadIdx.x & 63;
  const int wib  = threadIdx.x >> 6;
  const int total_patches = B * P;
  const float invK = 1.0f / (float)K;

  float wloss = 0.f, wcnt = 0.f;    // per-lane accumulators

  if (K == 256) {
    // ------- fast path: patch-per-row, 16 pixels/lane -----------------
    const int row = lane >> 4;       // 0..3 -> patch within wave
    const int col = lane & 15;       // lane within row
    const int poff = col * 16;       // this lane's 16-pixel chunk
    const int wave_stride = gridDim.x * WPB * PPW;

    for (int pbase = (blockIdx.x * WPB + wib) * PPW; pbase < total_patches;
         pbase += wave_stride) {
      const int patch = pbase + row;
      const bool row_ok = patch < total_patches;
      const long base = (row_ok ? (long)patch * 256L : 0L) + poff;

      float4 xa[4], ya[4]; int4 ma[4];
      #pragma unroll
      for (int j = 0; j < 4; ++j) {
        xa[j] = *(const float4*)(xg + base + 4 * j);
        ya[j] = *(const float4*)(yg + base + 4 * j);
        ma[j] = *(const int4*)(mg + base + 4 * j);
      }
      const float* xr = (const float*)xa;
      const float* yr = (const float*)ya;
      const int*   mi = (const int*)ma;
      float wv[16];

      // -- pass 1: WLS sums (msum/symsum reduced with batch 2) ---------
      float sw = 0.f, swx = 0.f, swy = 0.f, swxx = 0.f, swxy = 0.f;
      float msum = 0.f, symsum = 0.f;
      #pragma unroll
      for (int i = 0; i < 16; ++i) {
        const float m = mi[i] ? 1.f : 0.f;
        const float xx = xr[i], yy = yr[i];
        const float w = m * frcp(fmaxf(yy, 1e-5f));
        wv[i] = w;
        const float wx = w * xx;
        sw += w; swx += wx; swy = fmaf(w, yy, swy);
        swxx = fmaf(wx, xx, swxx); swxy = fmaf(wx, yy, swxy);
        msum += m; symsum = fmaf(m, yy, symsum);
      }
      sw = rowredu(sw); swx = rowredu(swx); swy = rowredu(swy);
      swxx = rowredu(swxx); swxy = rowredu(swxy);

      float det = sw * swxx - swx * swx;
      if (fabsf(det) < 1e-12f) det = 1e-12f;  // jnp.where -> +1e-12 any sign
      float rdet = frcp(det);
      const float s0 = (sw * swxy - swx * swy) * rdet;
      const float t0 = (swxx * swy - swx * swxy) * rdet;

      // -- pass 2: truncated refit (+ deferred mask stats) -------------
      float sw2 = 0.f, swx2 = 0.f, swy2 = 0.f, swxx2 = 0.f, swxy2 = 0.f;
      #pragma unroll
      for (int i = 0; i < 16; ++i) {
        const float xx = xr[i], yy = yr[i], w = wv[i];
        const float e = w * fabsf(fmaf(s0, xx, t0) - yy);
        const float w2 = (e < 1.0f) ? w : 0.f;  // TRUNC = 1.0, strict <
        const float w2x = w2 * xx;
        sw2 += w2; swx2 += w2x; swy2 = fmaf(w2, yy, swy2);
        swxx2 = fmaf(w2x, xx, swxx2); swxy2 = fmaf(w2x, yy, swxy2);
      }
      sw2 = rowredu(sw2); swx2 = rowredu(swx2); swy2 = rowredu(swy2);
      swxx2 = rowredu(swxx2); swxy2 = rowredu(swxy2);
      msum = rowredu(msum); symsum = rowredu(symsum);

      if (sw2 > 1e-8f) {  // sum(w2)==sw2; else fall back to pass-1 sums
        sw = sw2; swx = swx2; swy = swy2; swxx = swxx2; swxy = swxy2;
      }
      det = sw * swxx - swx * swx;
      if (fabsf(det) < 1e-12f) det = 1e-12f;
      rdet = frcp(det);
      const float s = (sw * swxy - swx * swy) * rdet;
      const float t = (swxx * swy - swx * swxy) * rdet;

      // -- pass 3: smooth-L1 patch loss --------------------------------
      const float mean_depth =
          (msum > 0.f) ? (symsum * frcp(fmaxf(msum, 1.f))) : 1.f;
      const float yfloor = 0.1f * mean_depth;

      float lsum = 0.f;
      #pragma unroll
      for (int i = 0; i < 16; ++i) {
        const float m = (wv[i] > 0.f) ? 1.f : 0.f;  // recover mask from w
        const float pw = m * frcp(fmaxf(yr[i], yfloor));
        const float err = fabsf(fmaf(s, xr[i], t) - yr[i]) * pw;
        // BETA = 0.1: err<0.1 ? 0.5*err^2/0.1 : err-0.05
        lsum += (err < 0.1f) ? (5.0f * err * err) : (err - 0.05f);
      }
      const float patch_loss = rowredu(lsum) * invK;

      // -- validity (row-uniform), accumulate on col==0 ---------------
      const int pidx = row_ok ? patch : (total_patches - 1);
      const float gs = gsg[(unsigned)pidx / (unsigned)P];
      const float ratio = s * frcp(fmaxf(gs, 1e-12f));
      const bool gs_ok = (gs > 0.f) ? (ratio >= 0.1f && ratio <= 10.0f) : true;
      const bool valid = (msum * invK >= 0.3f) && (s > 0.f) && gs_ok;

      if (col == 0 && row_ok && valid) { wloss += patch_loss; wcnt += 1.f; }
    }
  } else {
    // ------- generic path (any K): wave-per-patch ---------------------
    const int wave_stride = gridDim.x * WPB;
    for (int patch = blockIdx.x * WPB + wib; patch < total_patches;
         patch += wave_stride) {
      const long base = (long)patch * (long)K;
      const float* xp = xg + base;
      const float* yp = yg + base;
      const int*   mp = mg + base;

      float sw = 0.f, swx = 0.f, swy = 0.f, swxx = 0.f, swxy = 0.f;
      float msum = 0.f, symsum = 0.f;
      for (int j = lane; j < K; j += 64) {
        const float m = mp[j] ? 1.f : 0.f;
        const float xx = xp[j], yy = yp[j];
        const float w = m * frcp(fmaxf(yy, 1e-5f));
        const float wx = w * xx;
        sw += w; swx += wx; swy = fmaf(w, yy, swy);
        swxx = fmaf(wx, xx, swxx); swxy = fmaf(wx, yy, swxy);
        msum += m; symsum = fmaf(m, yy, symsum);
      }
      sw = wredu(sw); swx = wredu(swx); swy = wredu(swy);
      swxx = wredu(swxx); swxy = wredu(swxy);
      msum = wredu(msum); symsum = wredu(symsum);

      float det = sw * swxx - swx * swx;
      if (fabsf(det) < 1e-12f) det = 1e-12f;
      float rdet = frcp(det);
      const float s0 = (sw * swxy - swx * swy) * rdet;
      const float t0 = (swxx * swy - swx * swxy) * rdet;

      float sw2 = 0.f, swx2 = 0.f, swy2 = 0.f, swxx2 = 0.f, swxy2 = 0.f;
      for (int j = lane; j < K; j += 64) {
        const float m = mp[j] ? 1.f : 0.f;
        const float xx = xp[j], yy = yp[j];
        const float w = m * frcp(fmaxf(yy, 1e-5f));
        const float e = w * fabsf(fmaf(s0, xx, t0) - yy);
        const float w2 = (e < 1.0f) ? w : 0.f;
        const float w2x = w2 * xx;
        sw2 += w2; swx2 += w2x; swy2 = fmaf(w2, yy, swy2);
        swxx2 = fmaf(w2x, xx, swxx2); swxy2 = fmaf(w2x, yy, swxy2);
      }
      sw2 = wredu(sw2); swx2 = wredu(swx2); swy2 = wredu(swy2);
      swxx2 = wredu(swxx2); swxy2 = wredu(swxy2);

      if (sw2 > 1e-8f) {
        sw = sw2; swx = swx2; swy = swy2; swxx = swxx2; swxy = swxy2;
      }
      det = sw * swxx - swx * swx;
      if (fabsf(det) < 1e-12f) det = 1e-12f;
      rdet = frcp(det);
      const float s = (sw * swxy - swx * swy) * rdet;
      const float t = (swxx * swy - swx * swxy) * rdet;

      const float mean_depth =
          (msum > 0.f) ? (symsum * frcp(fmaxf(msum, 1.f))) : 1.f;
      const float yfloor = 0.1f * mean_depth;

      float lsum = 0.f;
      for (int j = lane; j < K; j += 64) {
        const float m = mp[j] ? 1.f : 0.f;
        const float xx = xp[j], yy = yp[j];
        const float pw = m * frcp(fmaxf(yy, yfloor));
        const float err = fabsf(fmaf(s, xx, t) - yy) * pw;
        lsum += (err < 0.1f) ? (5.0f * err * err) : (err - 0.05f);
      }
      const float patch_loss = wredu(lsum) * invK;

      const float gs = gsg[(unsigned)patch / (unsigned)P];
      const float ratio = s * frcp(fmaxf(gs, 1e-12f));
      const bool gs_ok = (gs > 0.f) ? (ratio >= 0.1f && ratio <= 10.0f) : true;
      const bool valid = (msum * invK >= 0.3f) && (s > 0.f) && gs_ok;

      if (lane == 0 && valid) { wloss += patch_loss; wcnt += 1.f; }
    }
  }

  // ---- wave reduce -> block reduce (LDS) -> 2 atomics per block ------
  wloss = wredu(wloss);
  wcnt  = wredu(wcnt);
  __shared__ float sl[WPB], sc[WPB];
  if (lane == 0) { sl[wib] = wloss; sc[wib] = wcnt; }
  __syncthreads();
  if (threadIdx.x == 0) {
    float bl = 0.f, bc = 0.f;
    #pragma unroll
    for (int i = 0; i < WPB; ++i) { bl += sl[i]; bc += sc[i]; }
    const int slot = (blockIdx.x & (NSLOTS - 1)) * 32;  // own 128-B line
    atomicAdd(&ws[slot], bl);
    atomicAdd(&ws[slot + 1], bc);
  }
}

__global__ void finalize_kernel(const float* __restrict__ ws,
                                float* __restrict__ out) {
  const int t = threadIdx.x;  // 64 threads
  float l = wredu(ws[t * 32]);
  float c = wredu(ws[t * 32 + 1]);
  if (t == 0) out[0] = (c > 0.f) ? (l / fmaxf(c, 1.f)) : 0.f;
}

extern "C" void kernel_launch(void* const* d_in, const int* in_sizes, int n_in,
                              void* d_out, int out_size, void* d_ws, size_t ws_size,
                              hipStream_t stream) {
  const float* pred = (const float*)d_in[0];
  const float* gt   = (const float*)d_in[1];
  const int*   mask = (const int*)d_in[2];
  const float* gs   = (const float*)d_in[3];
  const int*   pP   = (const int*)d_in[4];
  const int*   pK   = (const int*)d_in[5];
  const int B = in_sizes[3];
  const long total_pixels = (long)in_sizes[0];
  float* ws = (float*)d_ws;

  // 64 slot-lines zeroed by a memset node (8 KB)
  hipMemsetAsync(ws, 0, NSLOTS * 32 * sizeof(float), stream);

  // grid sized for K=256: 16 patches per block (4 waves x 4 rows)
  long est_patches = total_pixels / 256;
  long blocks = (est_patches + WPB * PPW - 1) / (WPB * PPW);
  if (blocks < 1) blocks = 1;
  if (blocks > MAXBLK) blocks = MAXBLK;
  moge_patch_kernel<<<(int)blocks, 256, 0, stream>>>(pred, gt, mask, gs, pP,
                                                     pK, B, ws);
  finalize_kernel<<<1, 64, 0, stream>>>(ws, (float*)d_out);
}